// Round 21
// baseline (119.520 us; speedup 1.0000x reference)
//
#include <hip/hip_runtime.h>

#define N_NODES   100000
#define FIELD_DIM 128
#define EMBED_DIM 64
#define N_EDGES   3200000
#define NX        16384   // BATCH * NUM_FIELDS

#define NRANGE    2
#define RN        50000   // nodes per histogram range
#define RNH       25000   // packed u32 bins per range
#define NSLICE    125     // edge slices
#define SLICE_E   (N_EDGES / NSLICE)   // 25600 (< 65536: u16-safe per slice)
#define HISTB     (NRANGE * NSLICE)    // 250 hist blocks
#define SB_N      16384                 // sbase_t row width (u32)
#define GEMMB     ((N_NODES + 63) / 64) // 1563 gemm blocks
#define PCAP      5120                  // pairs capacity per slice (mean ~3950)

typedef short  bf16x8 __attribute__((ext_vector_type(8)));
typedef float  f32x4  __attribute__((ext_vector_type(4)));

__device__ __forceinline__ unsigned short f2bf(float x) {
    unsigned u = __float_as_uint(x);
    u += 0x7FFF + ((u >> 16) & 1);          // round-to-nearest-even
    return (unsigned short)(u >> 16);
}
__device__ __forceinline__ float bf2f(unsigned short b) {
    return __uint_as_float(((unsigned)b) << 16);
}
__device__ __forceinline__ unsigned pk2(float lo, float hi) {
    return (unsigned)f2bf(lo) | ((unsigned)f2bf(hi) << 16);
}

// ---------------- zero scur16 + counters + bits (20544 B = 1284 float4) ----
__global__ void k_zero(float4* __restrict__ z4) {
    int i = blockIdx.x * blockDim.x + threadIdx.x;
    if (i < 1284) z4[i] = make_float4(0.f, 0.f, 0.f, 0.f);
}

// ---------------- init: bitmap of needed nodes (blocks 0..63) + W^T --------
__global__ void k_init(const int* __restrict__ x, unsigned int* __restrict__ bits,
                       const float* __restrict__ W, unsigned short* __restrict__ Wt) {
    int b = blockIdx.x;
    if (b < 64) {
        int i = b * 256 + threadIdx.x;      // NX = 64*256 exactly
        int v = x[i];
        atomicOr(&bits[v >> 5], 1u << (v & 31));
    } else {
        for (int o = threadIdx.x; o < FIELD_DIM * EMBED_DIM; o += 256) {
            int c = o >> 7, k = o & 127;
            Wt[o] = f2bf(W[k * EMBED_DIM + c]);
        }
    }
}

// ---------------- fused hist + extract (2 ranges x 125 slices) -------------
// Block (s<<1)|q: histogram of dst in range q (packed-u16 LDS bins).
// Range-0 blocks ALSO extract flagged (dst,src) pairs into the per-slice
// dense stream. LAYOUT INVARIANT: pairs overlays h16 (NOT partial32) — both
// are written here / before gemm, and pairs is consumed by k_place BEFORE
// k_gemm overwrites h16.
__global__ __launch_bounds__(1024) void k_histex(const int* __restrict__ dst,
                                                 const int* __restrict__ src,
                                                 const unsigned int* __restrict__ bits,
                                                 unsigned int* __restrict__ partial32,
                                                 int2* __restrict__ pairs,
                                                 int* __restrict__ scur16) {
    __shared__ unsigned int hist[RNH];        // 100,000 B (2 bins per u32)
    __shared__ int wsum[16];
    __shared__ int sbase_sh;
    int tid = threadIdx.x;
    int q = blockIdx.x & 1, s = blockIdx.x >> 1;
    for (int i = tid; i < RNH; i += 1024) hist[i] = 0;
    __syncthreads();
    int lo = q * RN;
    const int4* dp = (const int4*)(dst + s * SLICE_E);
    const int4* sp = (const int4*)(src + s * SLICE_E);
    int lane = tid & 63, w = tid >> 6;
    int2* po = pairs + (size_t)s * PCAP;

    for (int it = 0; it < 7; ++it) {          // ceil(6400/1024) = 7
        int i = it * 1024 + tid;
        bool act = (i < SLICE_E / 4);
        int4 d = act ? dp[i] : make_int4(0, 0, 0, 0);
        int dd[4] = {d.x, d.y, d.z, d.w};
        // histogram (own range only)
#pragma unroll
        for (int u = 0; u < 4; ++u) {
            int a = dd[u] - lo;
            if (act && (unsigned)a < RN)
                atomicAdd(&hist[a >> 1], 1u << ((a & 1) << 4));
        }
        if (q == 0) {                         // block-uniform branch
            int4 s4 = act ? sp[i] : make_int4(0, 0, 0, 0);
            int ss[4] = {s4.x, s4.y, s4.z, s4.w};
            bool fl[4];
            int nf = 0;
#pragma unroll
            for (int u = 0; u < 4; ++u) {
                fl[u] = act && ((bits[(unsigned)dd[u] >> 5] >> (dd[u] & 31)) & 1u);
                nf += fl[u] ? 1 : 0;
            }
            int incl = nf;
#pragma unroll
            for (int o = 1; o < 64; o <<= 1) {
                int t = __shfl_up(incl, o);
                if (lane >= o) incl += t;
            }
            if (lane == 63) wsum[w] = incl;
            __syncthreads();
            if (tid == 0) {
                int bt = 0;
#pragma unroll
                for (int g = 0; g < 16; ++g) bt += wsum[g];
                sbase_sh = bt ? atomicAdd(&scur16[s * 16], bt) : 0;
            }
            __syncthreads();
            int wbase = 0;
            for (int g = 0; g < w; ++g) wbase += wsum[g];
            int pos = sbase_sh + wbase + incl - nf;
#pragma unroll
            for (int u = 0; u < 4; ++u) {
                if (fl[u]) {
                    if (pos < PCAP) po[pos] = make_int2(dd[u], ss[u]);
                    ++pos;
                }
            }
            __syncthreads();                  // protect wsum reuse next iter
        }
    }
    __syncthreads();
    unsigned int* pw = partial32 + (size_t)blockIdx.x * RNH;
    for (int i = tid; i < RNH; i += 1024) pw[i] = hist[i];
}

// ---------------- reduce + compaction + sbase_t (register-resident) --------
__global__ __launch_bounds__(256) void k_reduce(const unsigned int* __restrict__ partial32,
                                                const unsigned int* __restrict__ bits,
                                                int* __restrict__ cnt,
                                                float* __restrict__ dinv,
                                                int* __restrict__ nlist,
                                                int* __restrict__ inv,
                                                int* __restrict__ off,
                                                int* __restrict__ sbase_t,
                                                unsigned long long* __restrict__ counters) {
    __shared__ int wtot[4], wedge[4], ptot[4], pedge[4];
    __shared__ unsigned int baseN, baseE;
    int tid = threadIdx.x;
    int v = blockIdx.x * 256 + tid;
    bool inb = (v < N_NODES);
    int vc = inb ? v : (N_NODES - 1);
    int q = vc / RN, loc = vc - q * RN;
    int i2 = loc >> 1, sh = (loc & 1) << 4;
    const unsigned int* p = partial32 + (size_t)q * RNH + i2;
    unsigned short vals[NSLICE];
#pragma unroll
    for (int s = 0; s < NSLICE; ++s)
        vals[s] = (unsigned short)((p[(size_t)s * (NRANGE * RNH)] >> sh) & 0xFFFFu);
    int c = 0;
#pragma unroll
    for (int s = 0; s < NSLICE; ++s) c += vals[s];
    if (inb) {
        cnt[v] = c;
        dinv[v] = rsqrtf((float)c + 1.0f);    // +1 self loop
    }
    bool fl = inb && ((bits[v >> 5] >> (v & 31)) & 1u);
    int lane = tid & 63;
    int w = tid >> 6;
    unsigned long long mask = __ballot(fl);
    int cc = fl ? c : 0;
    int incl = cc;
#pragma unroll
    for (int o = 1; o < 64; o <<= 1) {
        int t = __shfl_up(incl, o);
        if (lane >= o) incl += t;
    }
    if (lane == 63) { wtot[w] = __popcll(mask); wedge[w] = incl; }
    int myi = __popcll(mask & ((1ull << lane) - 1));
    int excl = incl - cc;
    __syncthreads();
    if (tid == 0) {
        int t0 = wtot[0], t1 = wtot[1], t2 = wtot[2], t3 = wtot[3];
        int e0 = wedge[0], e1 = wedge[1], e2 = wedge[2], e3 = wedge[3];
        ptot[0] = 0; ptot[1] = t0; ptot[2] = t0 + t1; ptot[3] = t0 + t1 + t2;
        pedge[0] = 0; pedge[1] = e0; pedge[2] = e0 + e1; pedge[3] = e0 + e1 + e2;
        int bt = t0 + t1 + t2 + t3;
        int be = e0 + e1 + e2 + e3;
        if (bt > 0) {
            unsigned long long add = ((unsigned long long)(unsigned)be << 32) |
                                     (unsigned long long)(unsigned)bt;
            unsigned long long old = atomicAdd(counters, add);
            baseN = (unsigned)(old & 0xFFFFFFFFull);
            baseE = (unsigned)(old >> 32);
        } else {
            baseN = 0; baseE = 0;
        }
    }
    __syncthreads();
    if (fl) {
        int ic = (int)baseN + ptot[w] + myi;
        int oc = (int)baseE + pedge[w] + excl;
        nlist[ic] = v;
        inv[v] = ic;
        off[v] = oc;
        int cum = 0;
#pragma unroll
        for (int s = 0; s < NSLICE; ++s) {
            sbase_t[(size_t)s * SB_N + ic] = oc + cum;
            cum += vals[s];
        }
    }
}

// ---------------- place: absolute LDS cursors; inv lookup in dense loop ----
// MUST run BEFORE k_gemm (pairs overlays h16).
__global__ __launch_bounds__(1024) void k_place(const int2* __restrict__ pairs,
                                                const int* __restrict__ scur16,
                                                const int* __restrict__ inv,
                                                const int* __restrict__ sbase_t,
                                                int* __restrict__ elist) {
    __shared__ int cur[SB_N];                  // 64 KB absolute cursors
    int s = blockIdx.x, tid = threadIdx.x;
    const int* srow = sbase_t + (size_t)s * SB_N;
    for (int i = tid; i < SB_N; i += 1024) cur[i] = srow[i];
    __syncthreads();
    int tot = min(scur16[s * 16], PCAP);
    const int2* pp = pairs + (size_t)s * PCAP;
    for (int r = tid; r < tot; r += 1024) {
        int2 p = pp[r];
        int ii = inv[p.x];                     // p.x is flagged -> inv valid
        int slot = atomicAdd(&cur[ii], 1);
        elist[slot] = p.y;
    }
}

// ---------------- gemm: h(bf16) = F @ W via MFMA 16x16x32, B in regs -------
__global__ __launch_bounds__(256) void k_gemm(const float* __restrict__ F,
                                              const unsigned short* __restrict__ Wt,
                                              unsigned short* __restrict__ h) {
    int tid = threadIdx.x;
    int wave = tid >> 6, lane = tid & 63;
    int l15 = lane & 15, kg = lane >> 4;

    const char* wb = (const char*)Wt;
    bf16x8 bfrag[4][4];
#pragma unroll
    for (int cb = 0; cb < 4; ++cb)
#pragma unroll
        for (int ks = 0; ks < 4; ++ks)
            bfrag[cb][ks] = *(const bf16x8*)(wb + (cb * 16 + l15) * 256 + ks * 64 + kg * 16);

    int row = blockIdx.x * 64 + wave * 16 + l15;
    int rowc = min(row, N_NODES - 1);              // clamp; stores are guarded
    const float4* F4 = (const float4*)(F + (size_t)rowc * FIELD_DIM + kg * 8);

    f32x4 acc[4];
#pragma unroll
    for (int cb = 0; cb < 4; ++cb) acc[cb] = (f32x4){0.f, 0.f, 0.f, 0.f};

#pragma unroll
    for (int ks = 0; ks < 4; ++ks) {               // K = 32 per step
        float4 fa = F4[ks * 8];
        float4 fb = F4[ks * 8 + 1];
        union { bf16x8 v; unsigned u[4]; } af;
        af.u[0] = pk2(fa.x, fa.y);
        af.u[1] = pk2(fa.z, fa.w);
        af.u[2] = pk2(fb.x, fb.y);
        af.u[3] = pk2(fb.z, fb.w);
#pragma unroll
        for (int cb = 0; cb < 4; ++cb)
            acc[cb] = __builtin_amdgcn_mfma_f32_16x16x32_bf16(af.v, bfrag[cb][ks],
                                                              acc[cb], 0, 0, 0);
    }
    int rbase = blockIdx.x * 64 + wave * 16 + kg * 4;
#pragma unroll
    for (int r = 0; r < 4; ++r) {
        int orow = rbase + r;
        if (orow < N_NODES) {
            unsigned short* hp = h + (size_t)orow * 64 + l15;
#pragma unroll
            for (int cb = 0; cb < 4; ++cb) hp[cb * 16] = f2bf(acc[cb][r]);
        }
    }
}

// ---------------- pull: one wave per flagged node, 8-deep gather pipe ------
__global__ __launch_bounds__(256) void k_pull(const int* __restrict__ nlist,
                                              const int* __restrict__ counters,
                                              const int* __restrict__ cnt,
                                              const int* __restrict__ off,
                                              const int* __restrict__ elist,
                                              const unsigned short* __restrict__ h,
                                              const float* __restrict__ dinv,
                                              const float* __restrict__ bias,
                                              float* __restrict__ accc) {
    int t = blockIdx.x * blockDim.x + threadIdx.x;
    int wid = t >> 6;              // wave id = compact node index
    int lane = t & 63;
    if (wid >= counters[0]) return;   // low 32 bits of packed u64 = node count
    int v = nlist[wid];
    float dvd = dinv[v];
    int deg = cnt[v];
    int base = off[v];
    float acc = bf2f(h[(size_t)v * 64 + lane]) * (dvd * dvd) + bias[lane];
    float acc2 = 0.f;
    int j = 0;
    for (; j + 7 < deg; j += 8) {
        int s0 = elist[base + j + 0];
        int s1 = elist[base + j + 1];
        int s2 = elist[base + j + 2];
        int s3 = elist[base + j + 3];
        int s4 = elist[base + j + 4];
        int s5 = elist[base + j + 5];
        int s6 = elist[base + j + 6];
        int s7 = elist[base + j + 7];
        float v0 = bf2f(h[(size_t)s0 * 64 + lane]);
        float v1 = bf2f(h[(size_t)s1 * 64 + lane]);
        float v2 = bf2f(h[(size_t)s2 * 64 + lane]);
        float v3 = bf2f(h[(size_t)s3 * 64 + lane]);
        float v4 = bf2f(h[(size_t)s4 * 64 + lane]);
        float v5 = bf2f(h[(size_t)s5 * 64 + lane]);
        float v6 = bf2f(h[(size_t)s6 * 64 + lane]);
        float v7 = bf2f(h[(size_t)s7 * 64 + lane]);
        float n0 = dinv[s0], n1 = dinv[s1], n2 = dinv[s2], n3 = dinv[s3];
        float n4 = dinv[s4], n5 = dinv[s5], n6 = dinv[s6], n7 = dinv[s7];
        acc  += v0 * (n0 * dvd);
        acc2 += v1 * (n1 * dvd);
        acc  += v2 * (n2 * dvd);
        acc2 += v3 * (n3 * dvd);
        acc  += v4 * (n4 * dvd);
        acc2 += v5 * (n5 * dvd);
        acc  += v6 * (n6 * dvd);
        acc2 += v7 * (n7 * dvd);
    }
    for (; j < deg; ++j) {
        int s0 = elist[base + j];
        acc += bf2f(h[(size_t)s0 * 64 + lane]) * (dinv[s0] * dvd);
    }
    accc[(size_t)wid * 64 + lane] = acc + acc2;
}

// ---------------- final gather: out[b] = accc[inv[x[b]]] -------------------
__global__ void k_gather(const int* __restrict__ x,
                         const int* __restrict__ inv,
                         const float* __restrict__ accc,
                         float* __restrict__ out) {
    int g = blockIdx.x * blockDim.x + threadIdx.x;   // [0, NX*64)
    if (g >= NX * 64) return;
    int v = x[g >> 6];
    out[g] = accc[(size_t)inv[v] * 64 + (g & 63)];
}

extern "C" void kernel_launch(void* const* d_in, const int* in_sizes, int n_in,
                              void* d_out, int out_size, void* d_ws, size_t ws_size,
                              hipStream_t stream) {
    const float* features = (const float*)d_in[0];
    const int*   edge     = (const int*)d_in[1];
    const float* W        = (const float*)d_in[2];
    const float* bias     = (const float*)d_in[3];
    const int*   x        = (const int*)d_in[4];
    float* out = (float*)d_out;

    char* ws = (char*)d_ws;
    // Overlay plan (producer -> consumer ordering enforced by launch order):
    //   pairs   [0 .. 5.12M)   overlays h16: written by histex, read by place,
    //                          then gemm overwrites h16. place MUST precede gemm.
    //   accc    [21.92M)       overlays partial32 tail: partial32 dead after reduce.
    unsigned short* h16      = (unsigned short*)(ws);            // 12,800,000 B
    int2*           pairs    = (int2*)(ws);                      //  5,120,000 B (overlay h16)
    int*            elist    = (int*)(ws + 12800000);            //  4,000,000 B (~494K used)
    unsigned int*   partial32= (unsigned int*)(ws + 16800000);   // 25,000,000 B (dead after reduce)
    float*          accc     = (float*)(ws + 21920000);          //  4,194,304 B overlays partial32
    int*            sbase_t  = (int*)  (ws + 41800000);          //  8,192,000 B (125 x 16384 u32)
    int*            cnt      = (int*)  (ws + 49992000);          //    400,000 B
    float*          dinv     = (float*)(ws + 50392000);          //    400,000 B
    int*            off      = (int*)  (ws + 50792000);          //    400,000 B
    int*            inv      = (int*)  (ws + 51192000);          //    400,000 B
    int*            nlist    = (int*)  (ws + 51592000);          //     65,536 B
    int*            scur16   = (int*)  (ws + 51657536);          //      8,000 B (125 x 16 ints)
    unsigned long long* counters = (unsigned long long*)(ws + 51665536); // 32 B
    unsigned int*   bits     = (unsigned int*) (ws + 51665568);  //     12,512 B
    unsigned short* Wt       = (unsigned short*)(ws + 51678080); //     16,384 B
    // zero region: scur16+counters+bits = 51657536 .. 51678080 = 20,544 B = 1284 float4

    const int* esrc = edge;
    const int* edst = edge + N_EDGES;

    k_zero  <<<6, 256, 0, stream>>>((float4*)(ws + 51657536));
    k_init  <<<65, 256, 0, stream>>>(x, bits, W, Wt);
    k_histex<<<HISTB, 1024, 0, stream>>>(edst, esrc, bits, partial32, pairs, scur16);
    k_reduce<<<(N_NODES + 255) / 256, 256, 0, stream>>>(partial32, bits, cnt, dinv,
                                                        nlist, inv, off, sbase_t, counters);
    k_place <<<NSLICE, 1024, 0, stream>>>(pairs, scur16, inv, sbase_t, elist);
    k_gemm  <<<GEMMB, 256, 0, stream>>>(features, Wt, h16);
    k_pull  <<<(NX * 64 + 255) / 256, 256, 0, stream>>>(nlist, (const int*)counters,
                                                        cnt, off, elist, h16, dinv,
                                                        bias, accc);
    k_gather<<<(NX * 64 + 255) / 256, 256, 0, stream>>>(x, inv, accc, out);
}

// Round 22
// 107.085 us; speedup vs baseline: 1.1161x; 1.1161x over previous
//
#include <hip/hip_runtime.h>

#define N_NODES   100000
#define FIELD_DIM 128
#define EMBED_DIM 64
#define N_EDGES   3200000
#define NX        16384   // BATCH * NUM_FIELDS

#define NRANGE    2
#define RN        50000   // nodes per histogram range
#define RNH       25000   // packed u32 bins per range
#define NSLICE    125     // edge slices
#define SLICE_E   (N_EDGES / NSLICE)   // 25600 (< 65536: u16-safe per slice)
#define HISTB     (NRANGE * NSLICE)    // 250 hist blocks
#define SB_N      16384                 // sbase_t row width (u32)
#define EXB       625                   // extract blocks: 5120 edges each, 5 per slice
#define GEMMB     ((N_NODES + 63) / 64) // 1563 gemm blocks
#define EGB       (EXB + GEMMB)         // 2188 fused blocks
#define PCAP      5120                  // pairs capacity per slice (mean 3950)

typedef short  bf16x8 __attribute__((ext_vector_type(8)));
typedef float  f32x4  __attribute__((ext_vector_type(4)));

__device__ __forceinline__ unsigned short f2bf(float x) {
    unsigned u = __float_as_uint(x);
    u += 0x7FFF + ((u >> 16) & 1);          // round-to-nearest-even
    return (unsigned short)(u >> 16);
}
__device__ __forceinline__ float bf2f(unsigned short b) {
    return __uint_as_float(((unsigned)b) << 16);
}
__device__ __forceinline__ unsigned pk2(float lo, float hi) {
    return (unsigned)f2bf(lo) | ((unsigned)f2bf(hi) << 16);
}

// ---------------- zero scur16 + counters + bits (20544 B = 1284 float4) ----
__global__ void k_zero(float4* __restrict__ z4) {
    int i = blockIdx.x * blockDim.x + threadIdx.x;
    if (i < 1284) z4[i] = make_float4(0.f, 0.f, 0.f, 0.f);
}

// ---------------- init: bitmap of needed nodes (blocks 0..63) + W^T --------
__global__ void k_init(const int* __restrict__ x, unsigned int* __restrict__ bits,
                       const float* __restrict__ W, unsigned short* __restrict__ Wt) {
    int b = blockIdx.x;
    if (b < 64) {
        int i = b * 256 + threadIdx.x;      // NX = 64*256 exactly
        int v = x[i];
        atomicOr(&bits[v >> 5], 1u << (v & 31));
    } else {
        for (int o = threadIdx.x; o < FIELD_DIM * EMBED_DIM; o += 256) {
            int c = o >> 7, k = o & 127;
            Wt[o] = f2bf(W[k * EMBED_DIM + c]);
        }
    }
}

// ---------------- degree histogram: packed-u16 LDS, 2 ranges x 125 slices --
__global__ __launch_bounds__(1024) void k_hist(const int* __restrict__ dst,
                                               unsigned int* __restrict__ partial32) {
    __shared__ unsigned int hist[RNH];        // 100,000 B (2 bins per u32)
    int tid = threadIdx.x;
    int q = blockIdx.x & 1, s = blockIdx.x >> 1;
    for (int i = tid; i < RNH; i += 1024) hist[i] = 0;
    __syncthreads();
    int lo = q * RN;
    const int4* dp = (const int4*)(dst + s * SLICE_E);
    for (int i = tid; i < SLICE_E / 4; i += 1024) {
        int4 d = dp[i];
        int a;
        a = d.x - lo; if ((unsigned)a < RN) atomicAdd(&hist[a >> 1], 1u << ((a & 1) << 4));
        a = d.y - lo; if ((unsigned)a < RN) atomicAdd(&hist[a >> 1], 1u << ((a & 1) << 4));
        a = d.z - lo; if ((unsigned)a < RN) atomicAdd(&hist[a >> 1], 1u << ((a & 1) << 4));
        a = d.w - lo; if ((unsigned)a < RN) atomicAdd(&hist[a >> 1], 1u << ((a & 1) << 4));
    }
    __syncthreads();
    unsigned int* po = partial32 + (size_t)blockIdx.x * RNH;
    for (int i = tid; i < RNH; i += 1024) po[i] = hist[i];
}

// ---------------- reduce + compaction + sbase_t (register-resident) --------
__global__ __launch_bounds__(256) void k_reduce(const unsigned int* __restrict__ partial32,
                                                const unsigned int* __restrict__ bits,
                                                int* __restrict__ cnt,
                                                float* __restrict__ dinv,
                                                int* __restrict__ nlist,
                                                int* __restrict__ inv,
                                                int* __restrict__ off,
                                                int* __restrict__ sbase_t,
                                                unsigned long long* __restrict__ counters) {
    __shared__ int wtot[4], wedge[4], ptot[4], pedge[4];
    __shared__ unsigned int baseN, baseE;
    int tid = threadIdx.x;
    int v = blockIdx.x * 256 + tid;
    bool inb = (v < N_NODES);
    int vc = inb ? v : (N_NODES - 1);
    int q = vc / RN, loc = vc - q * RN;
    int i2 = loc >> 1, sh = (loc & 1) << 4;
    const unsigned int* p = partial32 + (size_t)q * RNH + i2;
    unsigned short vals[NSLICE];
#pragma unroll
    for (int s = 0; s < NSLICE; ++s)
        vals[s] = (unsigned short)((p[(size_t)s * (NRANGE * RNH)] >> sh) & 0xFFFFu);
    int c = 0;
#pragma unroll
    for (int s = 0; s < NSLICE; ++s) c += vals[s];
    if (inb) {
        cnt[v] = c;
        dinv[v] = rsqrtf((float)c + 1.0f);    // +1 self loop
    }
    bool fl = inb && ((bits[v >> 5] >> (v & 31)) & 1u);
    int lane = tid & 63;
    int w = tid >> 6;
    unsigned long long mask = __ballot(fl);
    int cc = fl ? c : 0;
    int incl = cc;
#pragma unroll
    for (int o = 1; o < 64; o <<= 1) {
        int t = __shfl_up(incl, o);
        if (lane >= o) incl += t;
    }
    if (lane == 63) { wtot[w] = __popcll(mask); wedge[w] = incl; }
    int myi = __popcll(mask & ((1ull << lane) - 1));
    int excl = incl - cc;
    __syncthreads();
    if (tid == 0) {
        int t0 = wtot[0], t1 = wtot[1], t2 = wtot[2], t3 = wtot[3];
        int e0 = wedge[0], e1 = wedge[1], e2 = wedge[2], e3 = wedge[3];
        ptot[0] = 0; ptot[1] = t0; ptot[2] = t0 + t1; ptot[3] = t0 + t1 + t2;
        pedge[0] = 0; pedge[1] = e0; pedge[2] = e0 + e1; pedge[3] = e0 + e1 + e2;
        int bt = t0 + t1 + t2 + t3;
        int be = e0 + e1 + e2 + e3;
        if (bt > 0) {
            unsigned long long add = ((unsigned long long)(unsigned)be << 32) |
                                     (unsigned long long)(unsigned)bt;
            unsigned long long old = atomicAdd(counters, add);
            baseN = (unsigned)(old & 0xFFFFFFFFull);
            baseE = (unsigned)(old >> 32);
        } else {
            baseN = 0; baseE = 0;
        }
    }
    __syncthreads();
    if (fl) {
        int ic = (int)baseN + ptot[w] + myi;
        int oc = (int)baseE + pedge[w] + excl;
        nlist[ic] = v;
        inv[v] = ic;
        off[v] = oc;
        int cum = 0;
#pragma unroll
        for (int s = 0; s < NSLICE; ++s) {
            sbase_t[(size_t)s * SB_N + ic] = oc + cum;
            cum += vals[s];
        }
    }
}

// ---------------- fused extract + gemm (every 3rd block = extract) ---------
// extract role: 625 blocks x 5120 edges (20/thread, 5 x int4 pipelined),
// ONE ballot/scan + ONE slice-cursor atomic per block (5 blocks per slice).
// gemm role: MFMA 16x16x32, B in registers. Both LDS-free.
__global__ __launch_bounds__(256) void k_exgemm(const int* __restrict__ src,
                                                const int* __restrict__ dst,
                                                const unsigned int* __restrict__ bits,
                                                const int* __restrict__ inv,
                                                int2* __restrict__ pairs,
                                                int* __restrict__ scur16,
                                                const float* __restrict__ F,
                                                const unsigned short* __restrict__ Wt,
                                                unsigned short* __restrict__ h) {
    int bk = blockIdx.x;
    int tid = threadIdx.x;
    bool ise = ((bk % 3) == 0) && (bk / 3 < EXB);
    if (ise) {
        // ---- extract role
        __shared__ int wsum[4];
        __shared__ int sbase;
        int b = bk / 3;                            // extract block id 0..624
        int lane = tid & 63, w = tid >> 6;
        int slice = b / 5;                         // 5 blocks per slice
        const int4* dp = (const int4*)(dst + b * 5120);
        const int4* sp = (const int4*)(src + b * 5120);
        int4 d4[5], s4[5];
#pragma unroll
        for (int u = 0; u < 5; ++u) d4[u] = dp[tid + 256 * u];
#pragma unroll
        for (int u = 0; u < 5; ++u) s4[u] = sp[tid + 256 * u];
        int dd[20], ss[20];
#pragma unroll
        for (int u = 0; u < 5; ++u) {
            dd[4 * u + 0] = d4[u].x; dd[4 * u + 1] = d4[u].y;
            dd[4 * u + 2] = d4[u].z; dd[4 * u + 3] = d4[u].w;
            ss[4 * u + 0] = s4[u].x; ss[4 * u + 1] = s4[u].y;
            ss[4 * u + 2] = s4[u].z; ss[4 * u + 3] = s4[u].w;
        }
        bool fl[20];
        int nf = 0;
#pragma unroll
        for (int u = 0; u < 20; ++u) {
            fl[u] = (bits[(unsigned)dd[u] >> 5] >> (dd[u] & 31)) & 1u;
            nf += fl[u] ? 1 : 0;
        }
        int incl = nf;
#pragma unroll
        for (int o = 1; o < 64; o <<= 1) {
            int t = __shfl_up(incl, o);
            if (lane >= o) incl += t;
        }
        if (lane == 63) wsum[w] = incl;
        __syncthreads();
        if (tid == 0) {
            int bt = wsum[0] + wsum[1] + wsum[2] + wsum[3];
            sbase = bt ? atomicAdd(&scur16[slice * 16], bt) : 0;
        }
        __syncthreads();
        int wbase = (w > 0 ? wsum[0] : 0) + (w > 1 ? wsum[1] : 0) + (w > 2 ? wsum[2] : 0);
        int pos = sbase + wbase + incl - nf;
        int2* po = pairs + (size_t)slice * PCAP;
#pragma unroll
        for (int u = 0; u < 20; ++u) {
            if (fl[u]) {
                if (pos < PCAP) po[pos] = make_int2(inv[dd[u]], ss[u]);
                ++pos;
            }
        }
        return;
    }
    // ---- gemm role
    int gb = bk - min(bk / 3 + 1, EXB);            // # extract blocks <= bk
    int wave = tid >> 6, lane = tid & 63;
    int l15 = lane & 15, kg = lane >> 4;

    const char* wb = (const char*)Wt;
    bf16x8 bfrag[4][4];
#pragma unroll
    for (int cb = 0; cb < 4; ++cb)
#pragma unroll
        for (int ks = 0; ks < 4; ++ks)
            bfrag[cb][ks] = *(const bf16x8*)(wb + (cb * 16 + l15) * 256 + ks * 64 + kg * 16);

    int row = gb * 64 + wave * 16 + l15;
    int rowc = min(row, N_NODES - 1);              // clamp; stores are guarded
    const float4* F4 = (const float4*)(F + (size_t)rowc * FIELD_DIM + kg * 8);

    f32x4 acc[4];
#pragma unroll
    for (int cb = 0; cb < 4; ++cb) acc[cb] = (f32x4){0.f, 0.f, 0.f, 0.f};

#pragma unroll
    for (int ks = 0; ks < 4; ++ks) {               // K = 32 per step
        float4 fa = F4[ks * 8];
        float4 fb = F4[ks * 8 + 1];
        union { bf16x8 v; unsigned u[4]; } af;
        af.u[0] = pk2(fa.x, fa.y);
        af.u[1] = pk2(fa.z, fa.w);
        af.u[2] = pk2(fb.x, fb.y);
        af.u[3] = pk2(fb.z, fb.w);
#pragma unroll
        for (int cb = 0; cb < 4; ++cb)
            acc[cb] = __builtin_amdgcn_mfma_f32_16x16x32_bf16(af.v, bfrag[cb][ks],
                                                              acc[cb], 0, 0, 0);
    }
    int rbase = gb * 64 + wave * 16 + kg * 4;
#pragma unroll
    for (int r = 0; r < 4; ++r) {
        int orow = rbase + r;
        if (orow < N_NODES) {
            unsigned short* hp = h + (size_t)orow * 64 + l15;
#pragma unroll
            for (int cb = 0; cb < 4; ++cb) hp[cb * 16] = f2bf(acc[cb][r]);
        }
    }
}

// ---------------- place: absolute LDS cursors, dense pair loop -------------
__global__ __launch_bounds__(1024) void k_place(const int2* __restrict__ pairs,
                                                const int* __restrict__ scur16,
                                                const int* __restrict__ sbase_t,
                                                int* __restrict__ elist) {
    __shared__ int cur[SB_N];                  // 64 KB absolute cursors
    int s = blockIdx.x, tid = threadIdx.x;
    const int* srow = sbase_t + (size_t)s * SB_N;
    for (int i = tid; i < SB_N; i += 1024) cur[i] = srow[i];
    __syncthreads();
    int tot = min(scur16[s * 16], PCAP);
    const int2* pp = pairs + (size_t)s * PCAP;
    for (int r = tid; r < tot; r += 1024) {
        int2 p = pp[r];
        int slot = atomicAdd(&cur[p.x], 1);
        elist[slot] = p.y;
    }
}

// ---------------- pull: one wave per flagged node, 8-deep gather pipe ------
__global__ __launch_bounds__(256) void k_pull(const int* __restrict__ nlist,
                                              const int* __restrict__ counters,
                                              const int* __restrict__ cnt,
                                              const int* __restrict__ off,
                                              const int* __restrict__ elist,
                                              const unsigned short* __restrict__ h,
                                              const float* __restrict__ dinv,
                                              const float* __restrict__ bias,
                                              float* __restrict__ accc) {
    int t = blockIdx.x * blockDim.x + threadIdx.x;
    int wid = t >> 6;              // wave id = compact node index
    int lane = t & 63;
    if (wid >= counters[0]) return;   // low 32 bits of packed u64 = node count
    int v = nlist[wid];
    float dvd = dinv[v];
    int deg = cnt[v];
    int base = off[v];
    float acc = bf2f(h[(size_t)v * 64 + lane]) * (dvd * dvd) + bias[lane];
    float acc2 = 0.f;
    int j = 0;
    for (; j + 7 < deg; j += 8) {
        int s0 = elist[base + j + 0];
        int s1 = elist[base + j + 1];
        int s2 = elist[base + j + 2];
        int s3 = elist[base + j + 3];
        int s4 = elist[base + j + 4];
        int s5 = elist[base + j + 5];
        int s6 = elist[base + j + 6];
        int s7 = elist[base + j + 7];
        float v0 = bf2f(h[(size_t)s0 * 64 + lane]);
        float v1 = bf2f(h[(size_t)s1 * 64 + lane]);
        float v2 = bf2f(h[(size_t)s2 * 64 + lane]);
        float v3 = bf2f(h[(size_t)s3 * 64 + lane]);
        float v4 = bf2f(h[(size_t)s4 * 64 + lane]);
        float v5 = bf2f(h[(size_t)s5 * 64 + lane]);
        float v6 = bf2f(h[(size_t)s6 * 64 + lane]);
        float v7 = bf2f(h[(size_t)s7 * 64 + lane]);
        float n0 = dinv[s0], n1 = dinv[s1], n2 = dinv[s2], n3 = dinv[s3];
        float n4 = dinv[s4], n5 = dinv[s5], n6 = dinv[s6], n7 = dinv[s7];
        acc  += v0 * (n0 * dvd);
        acc2 += v1 * (n1 * dvd);
        acc  += v2 * (n2 * dvd);
        acc2 += v3 * (n3 * dvd);
        acc  += v4 * (n4 * dvd);
        acc2 += v5 * (n5 * dvd);
        acc  += v6 * (n6 * dvd);
        acc2 += v7 * (n7 * dvd);
    }
    for (; j < deg; ++j) {
        int s0 = elist[base + j];
        acc += bf2f(h[(size_t)s0 * 64 + lane]) * (dinv[s0] * dvd);
    }
    accc[(size_t)wid * 64 + lane] = acc + acc2;
}

// ---------------- final gather: out[b] = accc[inv[x[b]]] -------------------
__global__ void k_gather(const int* __restrict__ x,
                         const int* __restrict__ inv,
                         const float* __restrict__ accc,
                         float* __restrict__ out) {
    int g = blockIdx.x * blockDim.x + threadIdx.x;   // [0, NX*64)
    if (g >= NX * 64) return;
    int v = x[g >> 6];
    out[g] = accc[(size_t)inv[v] * 64 + (g & 63)];
}

extern "C" void kernel_launch(void* const* d_in, const int* in_sizes, int n_in,
                              void* d_out, int out_size, void* d_ws, size_t ws_size,
                              hipStream_t stream) {
    const float* features = (const float*)d_in[0];
    const int*   edge     = (const int*)d_in[1];
    const float* W        = (const float*)d_in[2];
    const float* bias     = (const float*)d_in[3];
    const int*   x        = (const int*)d_in[4];
    float* out = (float*)d_out;

    char* ws = (char*)d_ws;
    // Overlays (r19-verified): pairs overlays partial32 (dead after reduce;
    // exgemm runs after reduce). accc overlays partial32 tail (written by pull).
    unsigned short* h16      = (unsigned short*)(ws);            // 12,800,000 B
    int*            elist    = (int*)(ws + 12800000);            //  4,000,000 B (~494K used)
    unsigned int*   partial32= (unsigned int*)(ws + 16800000);   // 25,000,000 B (dead after reduce)
    int2*           pairs    = (int2*)(ws + 16800000);           //  5,120,000 B overlays partial32
    float*          accc     = (float*)(ws + 21920000);          //  4,194,304 B overlays partial32
    int*            sbase_t  = (int*)  (ws + 41800000);          //  8,192,000 B (125 x 16384 u32)
    int*            cnt      = (int*)  (ws + 49992000);          //    400,000 B
    float*          dinv     = (float*)(ws + 50392000);          //    400,000 B
    int*            off      = (int*)  (ws + 50792000);          //    400,000 B
    int*            inv      = (int*)  (ws + 51192000);          //    400,000 B
    int*            nlist    = (int*)  (ws + 51592000);          //     65,536 B
    int*            scur16   = (int*)  (ws + 51657536);          //      8,000 B (125 x 16 ints)
    unsigned long long* counters = (unsigned long long*)(ws + 51665536); // 32 B
    unsigned int*   bits     = (unsigned int*) (ws + 51665568);  //     12,512 B
    unsigned short* Wt       = (unsigned short*)(ws + 51678080); //     16,384 B
    // zero region: scur16+counters+bits = 51657536 .. 51678080 = 20,544 B = 1284 float4

    const int* esrc = edge;
    const int* edst = edge + N_EDGES;

    k_zero  <<<6, 256, 0, stream>>>((float4*)(ws + 51657536));
    k_init  <<<65, 256, 0, stream>>>(x, bits, W, Wt);
    k_hist  <<<HISTB, 1024, 0, stream>>>(edst, partial32);
    k_reduce<<<(N_NODES + 255) / 256, 256, 0, stream>>>(partial32, bits, cnt, dinv,
                                                        nlist, inv, off, sbase_t, counters);
    k_exgemm<<<EGB, 256, 0, stream>>>(esrc, edst, bits, inv, pairs, scur16,
                                      features, Wt, h16);
    k_place <<<NSLICE, 1024, 0, stream>>>(pairs, scur16, sbase_t, elist);
    k_pull  <<<(NX * 64 + 255) / 256, 256, 0, stream>>>(nlist, (const int*)counters,
                                                        cnt, off, elist, h16, dinv,
                                                        bias, accc);
    k_gather<<<(NX * 64 + 255) / 256, 256, 0, stream>>>(x, inv, accc, out);
}